// Round 4
// baseline (122.190 us; speedup 1.0000x reference)
//
#include <hip/hip_runtime.h>

// B=8, N=512, D=64, E=32
// ws layout: src = ws[0 .. 4096*32), dst = ws[4096*32 .. 2*4096*32)  (1 MB)
//            probe scratch at ws + 2*BNE (results discarded)
#define BNE (4096 * 32)

// Kernel 1: src/dst projections. One wave per row; x-row pointer uniform.
__global__ __launch_bounds__(64) void proj_kernel(
    const float* __restrict__ x, const float* __restrict__ We,
    const float* __restrict__ be, const float* __restrict__ br,
    float* __restrict__ out, float* __restrict__ ws)
{
    const int lane = threadIdx.x;          // 0..63
    const int row  = blockIdx.x;           // 0..4095 = b*512 + i (uniform)
    const int proj = lane >> 5;            // 0 = src, 1 = dst
    const int e    = lane & 31;

    const float* __restrict__ xrow = x + (size_t)row * 64;        // uniform
    const float* __restrict__ wcol = We + proj * (64 * 32) + e;   // coalesced

    float acc = 0.0f;
    #pragma unroll
    for (int d = 0; d < 64; ++d)
        acc = fmaf(xrow[d], wcol[d * 32], acc);

    if (proj == 0) acc += be[e];

    ws[(size_t)proj * BNE + (size_t)row * 32 + e] = acc;

    if (blockIdx.x < 64) out[blockIdx.x * 64 + lane] = br[0];
}

// Kernel 2 (R2-best): delta[b,j] += sum_{i,e} relu(src+dst)*Wr. 2 j's/thread.
__global__ __launch_bounds__(256) void edge_kernel(
    const float* __restrict__ ws, const float* __restrict__ Wr,
    float* __restrict__ out)
{
    const float* __restrict__ src = ws;
    const float* __restrict__ dst = ws + BNE;

    const int b  = blockIdx.z;
    const int j0 = threadIdx.x;
    const int j1 = threadIdx.x + 256;
    const int i0 = blockIdx.x * 8;

    float d0[32], d1[32];
    const float4* __restrict__ dp0 = (const float4*)(dst + ((size_t)(b * 512 + j0)) * 32);
    const float4* __restrict__ dp1 = (const float4*)(dst + ((size_t)(b * 512 + j1)) * 32);
    #pragma unroll
    for (int k = 0; k < 8; ++k) {
        ((float4*)d0)[k] = dp0[k];
        ((float4*)d1)[k] = dp1[k];
    }

    float a00 = 0.f, a01 = 0.f, a10 = 0.f, a11 = 0.f;

    #pragma unroll 2
    for (int ii = 0; ii < 8; ++ii) {
        const int i = i0 + ii;
        const float* __restrict__ srow = src + ((size_t)(b * 512 + i)) * 32;  // uniform
        const float* __restrict__ wrow = Wr + (size_t)i * 32;                 // uniform
        #pragma unroll
        for (int e = 0; e < 32; e += 2) {
            const float s0 = srow[e],  s1 = srow[e + 1];
            const float w0 = wrow[e],  w1 = wrow[e + 1];
            a00 = fmaf(fmaxf(s0 + d0[e],     0.f), w0, a00);
            a01 = fmaf(fmaxf(s1 + d0[e + 1], 0.f), w1, a01);
            a10 = fmaf(fmaxf(s0 + d1[e],     0.f), w0, a10);
            a11 = fmaf(fmaxf(s1 + d1[e + 1], 0.f), w1, a11);
        }
    }

    atomicAdd(&out[b * 512 + j0], a00 + a01);
    atomicAdd(&out[b * 512 + j1], a10 + a11);
}

// MEASUREMENT PROBE: identical structure to edge_kernel but 64 i's per block
// (8x the work) so one dispatch ~= 8x T_edge and surfaces in the rocprof
// top-5 with real counters. Results stored to discarded ws scratch.
__global__ __launch_bounds__(256) void edge_probe(
    const float* __restrict__ ws, const float* __restrict__ Wr,
    float* __restrict__ scratch)
{
    const float* __restrict__ src = ws;
    const float* __restrict__ dst = ws + BNE;

    const int b  = blockIdx.z;
    const int j0 = threadIdx.x;
    const int j1 = threadIdx.x + 256;
    const int i0 = blockIdx.x * 8;

    float d0[32], d1[32];
    const float4* __restrict__ dp0 = (const float4*)(dst + ((size_t)(b * 512 + j0)) * 32);
    const float4* __restrict__ dp1 = (const float4*)(dst + ((size_t)(b * 512 + j1)) * 32);
    #pragma unroll
    for (int k = 0; k < 8; ++k) {
        ((float4*)d0)[k] = dp0[k];
        ((float4*)d1)[k] = dp1[k];
    }

    float a00 = 0.f, a01 = 0.f, a10 = 0.f, a11 = 0.f;

    #pragma unroll 2
    for (int ii = 0; ii < 64; ++ii) {                  // 8x the real i-range
        const int i = (i0 + ii) & 511;
        const float* __restrict__ srow = src + ((size_t)(b * 512 + i)) * 32;
        const float* __restrict__ wrow = Wr + (size_t)i * 32;
        #pragma unroll
        for (int e = 0; e < 32; e += 2) {
            const float s0 = srow[e],  s1 = srow[e + 1];
            const float w0 = wrow[e],  w1 = wrow[e + 1];
            a00 = fmaf(fmaxf(s0 + d0[e],     0.f), w0, a00);
            a01 = fmaf(fmaxf(s1 + d0[e + 1], 0.f), w1, a01);
            a10 = fmaf(fmaxf(s0 + d1[e],     0.f), w0, a10);
            a11 = fmaf(fmaxf(s1 + d1[e + 1], 0.f), w1, a11);
        }
    }

    // racing plain stores; values discarded (scratch is in re-poisoned ws)
    scratch[b * 512 + j0] = a00 + a01;
    scratch[b * 512 + j1] = a10 + a11;
}

extern "C" void kernel_launch(void* const* d_in, const int* in_sizes, int n_in,
                              void* d_out, int out_size, void* d_ws, size_t ws_size,
                              hipStream_t stream) {
    const float* x  = (const float*)d_in[0];   // (8,512,64)
    const float* We = (const float*)d_in[1];   // (128,32)
    const float* be = (const float*)d_in[2];   // (32,)
    const float* Wr = (const float*)d_in[3];   // (16384,1)
    const float* br = (const float*)d_in[4];   // (1,)
    float* out = (float*)d_out;                // (8,512,1) = 4096 floats
    float* ws  = (float*)d_ws;

    proj_kernel<<<4096, 64, 0, stream>>>(x, We, be, br, out, ws);
    edge_kernel<<<dim3(64, 1, 8), 256, 0, stream>>>(ws, Wr, out);
    // probe: measurement only, writes to discarded scratch
    edge_probe<<<dim3(64, 1, 8), 256, 0, stream>>>(ws, Wr, ws + 2 * BNE);
}

// Round 5
// 81.027 us; speedup vs baseline: 1.5080x; 1.5080x over previous
//
#include <hip/hip_runtime.h>

// B=8, N=512, D=64, E=32
// ws layout: src = ws[0 .. 4096*32), dst = ws[4096*32 .. 2*4096*32)  (1 MB)
#define BNE (4096 * 32)

// Kernel 1: src/dst projections. One wave per row; x-row pointer uniform
// (blockIdx-only) -> scalar-load path. lane = (proj, e). Folds be into src,
// inits out = br.
__global__ __launch_bounds__(64) void proj_kernel(
    const float* __restrict__ x, const float* __restrict__ We,
    const float* __restrict__ be, const float* __restrict__ br,
    float* __restrict__ out, float* __restrict__ ws)
{
    const int lane = threadIdx.x;          // 0..63
    const int row  = blockIdx.x;           // 0..4095 = b*512 + i (uniform)
    const int proj = lane >> 5;            // 0 = src, 1 = dst
    const int e    = lane & 31;

    const float* __restrict__ xrow = x + (size_t)row * 64;        // uniform
    const float* __restrict__ wcol = We + proj * (64 * 32) + e;   // coalesced

    float acc = 0.0f;
    #pragma unroll
    for (int d = 0; d < 64; ++d)
        acc = fmaf(xrow[d], wcol[d * 32], acc);

    if (proj == 0) acc += be[e];

    ws[(size_t)proj * BNE + (size_t)row * 32 + e] = acc;

    if (blockIdx.x < 64) out[blockIdx.x * 64 + lane] = br[0];
}

// Kernel 2: delta[b,j] += sum_{i in tile, e} relu(src[b,i,e]+dst[b,j,e]) * Wr[i*32+e]
// i-tile = 4 -> grid (128,8) = 1024 blocks = 4096 waves = 4 waves/SIMD
// (R4 probe showed 2 waves/SIMD left VALUBusy at 58%, latency-starved on the
// wave-uniform src/Wr broadcast loads; doubling TLP hides that latency.)
__global__ __launch_bounds__(256) void edge_kernel(
    const float* __restrict__ ws, const float* __restrict__ Wr,
    float* __restrict__ out)
{
    const float* __restrict__ src = ws;
    const float* __restrict__ dst = ws + BNE;

    const int b  = blockIdx.y;
    const int j0 = threadIdx.x;            // 0..255
    const int j1 = threadIdx.x + 256;      // 256..511
    const int i0 = blockIdx.x * 4;

    float d0[32], d1[32];
    const float4* __restrict__ dp0 = (const float4*)(dst + ((size_t)(b * 512 + j0)) * 32);
    const float4* __restrict__ dp1 = (const float4*)(dst + ((size_t)(b * 512 + j1)) * 32);
    #pragma unroll
    for (int k = 0; k < 8; ++k) {
        ((float4*)d0)[k] = dp0[k];
        ((float4*)d1)[k] = dp1[k];
    }

    float a00 = 0.f, a01 = 0.f, a10 = 0.f, a11 = 0.f;

    #pragma unroll
    for (int ii = 0; ii < 4; ++ii) {
        const int i = i0 + ii;
        const float* __restrict__ srow = src + ((size_t)(b * 512 + i)) * 32;  // uniform
        const float* __restrict__ wrow = Wr + (size_t)i * 32;                 // uniform
        #pragma unroll
        for (int e = 0; e < 32; e += 2) {
            const float s0 = srow[e],  s1 = srow[e + 1];
            const float w0 = wrow[e],  w1 = wrow[e + 1];
            a00 = fmaf(fmaxf(s0 + d0[e],     0.f), w0, a00);
            a01 = fmaf(fmaxf(s1 + d0[e + 1], 0.f), w1, a01);
            a10 = fmaf(fmaxf(s0 + d1[e],     0.f), w0, a10);
            a11 = fmaf(fmaxf(s1 + d1[e + 1], 0.f), w1, a11);
        }
    }

    atomicAdd(&out[b * 512 + j0], a00 + a01);
    atomicAdd(&out[b * 512 + j1], a10 + a11);
}

extern "C" void kernel_launch(void* const* d_in, const int* in_sizes, int n_in,
                              void* d_out, int out_size, void* d_ws, size_t ws_size,
                              hipStream_t stream) {
    const float* x  = (const float*)d_in[0];   // (8,512,64)
    const float* We = (const float*)d_in[1];   // (128,32)
    const float* be = (const float*)d_in[2];   // (32,)
    const float* Wr = (const float*)d_in[3];   // (16384,1)
    const float* br = (const float*)d_in[4];   // (1,)
    float* out = (float*)d_out;                // (8,512,1) = 4096 floats
    float* ws  = (float*)d_ws;

    proj_kernel<<<4096, 64, 0, stream>>>(x, We, be, br, out, ws);
    edge_kernel<<<dim3(128, 8), 256, 0, stream>>>(ws, Wr, out);
}

// Round 6
// 73.249 us; speedup vs baseline: 1.6681x; 1.1062x over previous
//
#include <hip/hip_runtime.h>

// B=8, N=512, D=64, E=32
// ws layout: src = ws[0 .. 4096*32), dst = ws[4096*32 .. 2*4096*32)  (1 MB)
#define BNE (4096 * 32)

// Kernel 1: src/dst projections. One wave per row; x-row pointer uniform
// (blockIdx-only) -> scalar-load path. lane = (proj, e). Folds be into src,
// inits out = br.
__global__ __launch_bounds__(64) void proj_kernel(
    const float* __restrict__ x, const float* __restrict__ We,
    const float* __restrict__ be, const float* __restrict__ br,
    float* __restrict__ out, float* __restrict__ ws)
{
    const int lane = threadIdx.x;          // 0..63
    const int row  = blockIdx.x;           // 0..4095 = b*512 + i (uniform)
    const int proj = lane >> 5;            // 0 = src, 1 = dst
    const int e    = lane & 31;

    const float* __restrict__ xrow = x + (size_t)row * 64;        // uniform
    const float* __restrict__ wcol = We + proj * (64 * 32) + e;   // coalesced

    float acc = 0.0f;
    #pragma unroll
    for (int d = 0; d < 64; ++d)
        acc = fmaf(xrow[d], wcol[d * 32], acc);

    if (proj == 0) acc += be[e];

    ws[(size_t)proj * BNE + (size_t)row * 32 + e] = acc;

    if (blockIdx.x < 64) out[blockIdx.x * 64 + lane] = br[0];
}

// Kernel 2 (best measured config, R2): delta[b,j] += sum_{i,e}
// relu(src[b,i,e]+dst[b,j,e]) * Wr[i*32+e]. Two j's per thread share each
// wave-uniform (src, Wr) scalar; i-tile = 8 -> grid (64,1,8) = 512 blocks.
// R4 probe: T ~= 6.6 us, VALUBusy 58%, hbm ~0 (L2-resident).
__global__ __launch_bounds__(256) void edge_kernel(
    const float* __restrict__ ws, const float* __restrict__ Wr,
    float* __restrict__ out)
{
    const float* __restrict__ src = ws;
    const float* __restrict__ dst = ws + BNE;

    const int b  = blockIdx.z;
    const int j0 = threadIdx.x;            // 0..255
    const int j1 = threadIdx.x + 256;      // 256..511
    const int i0 = blockIdx.x * 8;

    float d0[32], d1[32];
    const float4* __restrict__ dp0 = (const float4*)(dst + ((size_t)(b * 512 + j0)) * 32);
    const float4* __restrict__ dp1 = (const float4*)(dst + ((size_t)(b * 512 + j1)) * 32);
    #pragma unroll
    for (int k = 0; k < 8; ++k) {
        ((float4*)d0)[k] = dp0[k];
        ((float4*)d1)[k] = dp1[k];
    }

    float a00 = 0.f, a01 = 0.f, a10 = 0.f, a11 = 0.f;

    #pragma unroll 2
    for (int ii = 0; ii < 8; ++ii) {
        const int i = i0 + ii;
        const float* __restrict__ srow = src + ((size_t)(b * 512 + i)) * 32;  // uniform
        const float* __restrict__ wrow = Wr + (size_t)i * 32;                 // uniform
        #pragma unroll
        for (int e = 0; e < 32; e += 2) {
            const float s0 = srow[e],  s1 = srow[e + 1];
            const float w0 = wrow[e],  w1 = wrow[e + 1];
            a00 = fmaf(fmaxf(s0 + d0[e],     0.f), w0, a00);
            a01 = fmaf(fmaxf(s1 + d0[e + 1], 0.f), w1, a01);
            a10 = fmaf(fmaxf(s0 + d1[e],     0.f), w0, a10);
            a11 = fmaf(fmaxf(s1 + d1[e + 1], 0.f), w1, a11);
        }
    }

    atomicAdd(&out[b * 512 + j0], a00 + a01);
    atomicAdd(&out[b * 512 + j1], a10 + a11);
}

extern "C" void kernel_launch(void* const* d_in, const int* in_sizes, int n_in,
                              void* d_out, int out_size, void* d_ws, size_t ws_size,
                              hipStream_t stream) {
    const float* x  = (const float*)d_in[0];   // (8,512,64)
    const float* We = (const float*)d_in[1];   // (128,32)
    const float* be = (const float*)d_in[2];   // (32,)
    const float* Wr = (const float*)d_in[3];   // (16384,1)
    const float* br = (const float*)d_in[4];   // (1,)
    float* out = (float*)d_out;                // (8,512,1) = 4096 floats
    float* ws  = (float*)d_ws;

    proj_kernel<<<4096, 64, 0, stream>>>(x, We, be, br, out, ws);
    edge_kernel<<<dim3(64, 1, 8), 256, 0, stream>>>(ws, Wr, out);
}